// Round 8
// baseline (124.534 us; speedup 1.0000x reference)
//
#include <hip/hip_runtime.h>

#define NROIS 512
#define CH    256
#define SCALE 0.0625f
#define GAMMA 0.1f

typedef _Float16 h4 __attribute__((ext_vector_type(4)));
typedef float    f4 __attribute__((ext_vector_type(4)));   // native vec for NT builtins

// Transposed fp16 copy of x: (B,C,H,W) -> (B,H,W,C) halves. 32 MiB.
#define XT_BYTES ((size_t)4 * 128 * 128 * 256 * 2)

// ---------------------------------------------------------------------------
// Kernel 1: tiled transpose per batch: 256 (C) x 16384 (HW) -> 16384 x 256,
// converting fp32 -> fp16 at the write. 64 MiB read + 32 MiB write ~= HBM
// roofline (~16 us). x is read exactly once -> NON-TEMPORAL loads keep it
// from evicting L2 lines that the pool will want for xt.
// ---------------------------------------------------------------------------
__global__ __launch_bounds__(256) void transpose_kernel(
    const float* __restrict__ x, _Float16* __restrict__ xt)
{
    __shared__ float tile[64][65];           // [c][p], +1 pad
    const int bid = blockIdx.x;              // 256 p-tiles * 4 c-tiles * 4 batches
    const int pt  = bid & 255;
    const int ct  = (bid >> 8) & 3;
    const int b   = bid >> 10;
    const int p0  = pt * 64, c0 = ct * 64;
    const size_t boff = (size_t)b * (256 * 16384);
    const int a = threadIdx.x & 15;          // float4 slot
    const int r = threadIdx.x >> 4;          // 0..15

    #pragma unroll
    for (int i = 0; i < 4; ++i) {            // coalesced float4 reads along HW
        const int cr = r + 16 * i;
        const f4 v = __builtin_nontemporal_load(
            (const f4*)(x + boff + (size_t)(c0 + cr) * 16384 + p0 + 4 * a));
        tile[cr][4 * a + 0] = v.x;
        tile[cr][4 * a + 1] = v.y;
        tile[cr][4 * a + 2] = v.z;
        tile[cr][4 * a + 3] = v.w;
    }
    __syncthreads();
    #pragma unroll
    for (int i = 0; i < 4; ++i) {            // coalesced half4 writes along C
        const int pr = r + 16 * i;
        h4 v;
        v.x = (_Float16)tile[4 * a + 0][pr];
        v.y = (_Float16)tile[4 * a + 1][pr];
        v.z = (_Float16)tile[4 * a + 2][pr];
        v.w = (_Float16)tile[4 * a + 3][pr];
        *(h4*)(xt + boff + (size_t)(p0 + pr) * 256 + c0 + 4 * a) = v;
    }
}

// ---------------------------------------------------------------------------
// Kernel 2: ONE BLOCK (512 thr, 8 waves) PER ROI on fp16 xt. This is the
// harness-verified round-3 kernel (119.96 us) with one addition: the out
// epilogue uses NON-TEMPORAL stores (out is write-once, never re-read ->
// don't let 25.7 MB of output stream evict xt from L2/L3 mid-kernel).
//  - PROLOGUE: threads 0..48 precompute per-bin records into LDS:
//    4 clamped row offsets, 4 clamped col offsets (duplicate-clamp: index
//    min(d, n-1); duplicated cells carry weight 0), and 16 premultiplied
//    wy*wx weights.
//  - MAIN LOOP: branchless 16-load bins, 1-deep ping-pong pipeline:
//    issue bin i+1's loads, then FMA bin i under them. All buffer indices
//    compile-time. fmaf(0, finite, acc) == acc, so dup cells are exact.
// ---------------------------------------------------------------------------
__global__ __launch_bounds__(512, 4) void dcn_pool_roi_kernel(
    const _Float16* __restrict__ xt, const float* __restrict__ rois,
    const float* __restrict__ offs, float* __restrict__ out)
{
    __shared__ __align__(16) float res[CH * 49];    // 50176 B
    __shared__ __align__(16) int   s_ro[49][4];     // row element offsets
    __shared__ __align__(16) int   s_xo[49][4];     // col element offsets
    __shared__ __align__(16) float s_w[49][16];     // premultiplied weights
    const int n = blockIdx.x;

    const float* r = rois + n * 5;
    const int   b  = (int)r[0];
    const float x1 = r[1] * SCALE - 0.5f;
    const float y1 = r[2] * SCALE - 0.5f;
    const float rw = fmaxf(r[3] * SCALE - 0.5f - x1, 1.0f);
    const float rh = fmaxf(r[4] * SCALE - 0.5f - y1, 1.0f);
    const float bw = rw * (1.0f / 7.0f);
    const float bh = rh * (1.0f / 7.0f);

    const int t = threadIdx.x;

    // ---- prologue: per-bin weight records (threads 0..48) ----
    if (t < 49) {
        const int ph = t / 7, pw = t - ph * 7;
        const float offx = GAMMA * rw * offs[n * 98 + t];
        const float offy = GAMMA * rh * offs[n * 98 + 49 + t];
        const float xb = x1 + pw * bw + offx;
        const float yb = y1 + ph * bh + offy;
        const float qy = 0.25f * bh, qx = 0.25f * bw;

        float wy0 = 0.f, wy1 = 0.f, wy2 = 0.f, wy3 = 0.f;
        const int ymin = (int)fminf(fmaxf(yb + 0.5f * qy, 0.0f), 127.0f);
        #pragma unroll
        for (int iy = 0; iy < 4; ++iy) {
            const float ys = yb + ((float)iy + 0.5f) * qy;
            const float vy = ((ys > -1.0f) && (ys < 128.0f)) ? 0.25f : 0.0f;
            const float yc = fminf(fmaxf(ys, 0.0f), 127.0f);
            const int   y0 = (int)yc;            // >= ymin, <= ymin+2
            const float ly = yc - (float)y0;
            const float hy = 1.0f - ly;
            const int   dy = y0 - ymin;
            const float ha = hy * vy, la = ly * vy;
            wy0 += (dy == 0) ? ha : 0.0f;
            wy1 += (dy == 0) ? la : ((dy == 1) ? ha : 0.0f);
            wy2 += (dy == 1) ? la : ((dy == 2) ? ha : 0.0f);
            wy3 += (dy == 2) ? la : 0.0f;
        }
        float wx0 = 0.f, wx1 = 0.f, wx2 = 0.f, wx3 = 0.f;
        const int xmin = (int)fminf(fmaxf(xb + 0.5f * qx, 0.0f), 127.0f);
        #pragma unroll
        for (int ix = 0; ix < 4; ++ix) {
            const float xs = xb + ((float)ix + 0.5f) * qx;
            const float vx = ((xs > -1.0f) && (xs < 128.0f)) ? 0.25f : 0.0f;
            const float xc = fminf(fmaxf(xs, 0.0f), 127.0f);
            const int   x0 = (int)xc;
            const float lx = xc - (float)x0;
            const float hx = 1.0f - lx;
            const int   dx = x0 - xmin;
            const float ha = hx * vx, la = lx * vx;
            wx0 += (dx == 0) ? ha : 0.0f;
            wx1 += (dx == 0) ? la : ((dx == 1) ? ha : 0.0f);
            wx2 += (dx == 1) ? la : ((dx == 2) ? ha : 0.0f);
            wx3 += (dx == 2) ? la : 0.0f;
        }
        const int y0max = (int)fminf(fmaxf(yb + 3.5f * qy, 0.0f), 127.0f);
        const int x0max = (int)fminf(fmaxf(xb + 3.5f * qx, 0.0f), 127.0f);
        const int ny = min(y0max - ymin + 2, 128 - ymin);   // 1..4
        const int nx = min(x0max - xmin + 2, 128 - xmin);   // 1..4

        const float wyv[4] = {wy0, wy1, wy2, wy3};
        const float wxv[4] = {wx0, wx1, wx2, wx3};
        #pragma unroll
        for (int dy = 0; dy < 4; ++dy)
            s_ro[t][dy] = (ymin + min(dy, ny - 1)) * (128 * 256);
        #pragma unroll
        for (int dx = 0; dx < 4; ++dx)
            s_xo[t][dx] = (xmin + min(dx, nx - 1)) * 256;
        #pragma unroll
        for (int dy = 0; dy < 4; ++dy)
            #pragma unroll
            for (int dx = 0; dx < 4; ++dx)
                s_w[t][dy * 4 + dx] = wyv[dy] * wxv[dx];
    }
    __syncthreads();

    const int lane = threadIdx.x & 63;
    const int wv   = __builtin_amdgcn_readfirstlane(threadIdx.x >> 6); // 0..7
    const _Float16* base = xt + ((size_t)b << 22) + 4 * lane;

    h4 v0[4][4], v1[4][4];

#define ISSUE(V, BIN) do {                                                  \
        const int4 ro = *(const int4*)s_ro[BIN];                            \
        const int4 xo = *(const int4*)s_xo[BIN];                            \
        V[0][0] = *(const h4*)(base + ro.x + xo.x);                         \
        V[0][1] = *(const h4*)(base + ro.x + xo.y);                         \
        V[0][2] = *(const h4*)(base + ro.x + xo.z);                         \
        V[0][3] = *(const h4*)(base + ro.x + xo.w);                         \
        V[1][0] = *(const h4*)(base + ro.y + xo.x);                         \
        V[1][1] = *(const h4*)(base + ro.y + xo.y);                         \
        V[1][2] = *(const h4*)(base + ro.y + xo.z);                         \
        V[1][3] = *(const h4*)(base + ro.y + xo.w);                         \
        V[2][0] = *(const h4*)(base + ro.z + xo.x);                         \
        V[2][1] = *(const h4*)(base + ro.z + xo.y);                         \
        V[2][2] = *(const h4*)(base + ro.z + xo.z);                         \
        V[2][3] = *(const h4*)(base + ro.z + xo.w);                         \
        V[3][0] = *(const h4*)(base + ro.w + xo.x);                         \
        V[3][1] = *(const h4*)(base + ro.w + xo.y);                         \
        V[3][2] = *(const h4*)(base + ro.w + xo.z);                         \
        V[3][3] = *(const h4*)(base + ro.w + xo.w);                         \
    } while (0)

#define FMA_STORE(V, BIN) do {                                              \
        const float4 w0 = *(const float4*)&s_w[BIN][0];                     \
        const float4 w1 = *(const float4*)&s_w[BIN][4];                     \
        const float4 w2 = *(const float4*)&s_w[BIN][8];                     \
        const float4 w3 = *(const float4*)&s_w[BIN][12];                    \
        float4 acc = make_float4(0.0f, 0.0f, 0.0f, 0.0f);                   \
        const float wgt[16] = {w0.x, w0.y, w0.z, w0.w,                      \
                               w1.x, w1.y, w1.z, w1.w,                      \
                               w2.x, w2.y, w2.z, w2.w,                      \
                               w3.x, w3.y, w3.z, w3.w};                     \
        _Pragma("unroll")                                                   \
        for (int dy = 0; dy < 4; ++dy) {                                    \
            _Pragma("unroll")                                               \
            for (int dx = 0; dx < 4; ++dx) {                                \
                const float w  = wgt[dy * 4 + dx];                          \
                const h4    hv = V[dy][dx];                                 \
                acc.x = fmaf(w, (float)hv.x, acc.x);                        \
                acc.y = fmaf(w, (float)hv.y, acc.y);                        \
                acc.z = fmaf(w, (float)hv.z, acc.z);                        \
                acc.w = fmaf(w, (float)hv.w, acc.w);                        \
            }                                                               \
        }                                                                   \
        float* rp = res + (4 * lane) * 49 + (BIN);                          \
        rp[0]   = acc.x;                                                    \
        rp[49]  = acc.y;                                                    \
        rp[98]  = acc.z;                                                    \
        rp[147] = acc.w;                                                    \
    } while (0)

    // 1-deep ping-pong pipeline over this wave's bins (wv, wv+8, ...).
    ISSUE(v0, wv);
    #pragma unroll
    for (int i = 0; i < 7; ++i) {
        const int bin  = wv + 8 * i;
        if (bin >= 49) break;                 // wave-uniform
        const int nbin = bin + 8;
        if (i & 1) {
            if (nbin < 49) ISSUE(v0, nbin);
            FMA_STORE(v1, bin);
        } else {
            if (nbin < 49) ISSUE(v1, nbin);
            FMA_STORE(v0, bin);
        }
    }
#undef ISSUE
#undef FMA_STORE

    __syncthreads();

    // Coalesced epilogue: 12544 floats = 3136 float4, contiguous full-line
    // span owned entirely by this block. NON-TEMPORAL: out is write-once.
    float*    ob = out + (size_t)n * (CH * 49);
    const f4* rs = (const f4*)res;
    f4*       od = (f4*)ob;
    for (int i = t; i < 3136; i += 512)
        __builtin_nontemporal_store(rs[i], &od[i]);
}

// ---------------------------------------------------------------------------
// Fallback (round-1 kernel) if d_ws is too small. Reads fp32 x directly.
// ---------------------------------------------------------------------------
struct __attribute__((packed, aligned(4))) f2 { float x, y; };

__global__ __launch_bounds__(256) void dcn_pool_kernel(
    const float* __restrict__ x, const float* __restrict__ rois,
    const float* __restrict__ offs, float* __restrict__ out)
{
    const int bin = blockIdx.x;
    const int n   = bin / 49;
    const int pq  = bin - n * 49;
    const int ph  = pq / 7;
    const int pw  = pq - ph * 7;

    const float* r = rois + n * 5;
    const int   b  = (int)r[0];
    const float x1 = r[1] * SCALE - 0.5f;
    const float y1 = r[2] * SCALE - 0.5f;
    const float x2 = r[3] * SCALE - 0.5f;
    const float y2 = r[4] * SCALE - 0.5f;
    const float rw = fmaxf(x2 - x1, 1.0f);
    const float rh = fmaxf(y2 - y1, 1.0f);
    const float bw = rw * (1.0f / 7.0f);
    const float bh = rh * (1.0f / 7.0f);
    const float offx = GAMMA * rw * offs[n * 98 + pq];
    const float offy = GAMMA * rh * offs[n * 98 + 49 + pq];
    const float xb = x1 + pw * bw + offx;
    const float yb = y1 + ph * bh + offy;

    const int tid    = threadIdx.x;
    const int lane   = tid & 63;
    const int waveId = tid >> 6;
    const int idx    = lane & 31;
    const int s      = idx >> 1;
    const int rrow   = idx & 1;
    const int chHalf = lane >> 5;

    const int   iy = s >> 2, ix = s & 3;
    const float ys = yb + ((float)iy + 0.5f) * 0.25f * bh;
    const float xs = xb + ((float)ix + 0.5f) * 0.25f * bw;
    const bool  valid = (ys > -1.0f) & (ys < 128.0f) & (xs > -1.0f) & (xs < 128.0f);
    const float yc = fminf(fmaxf(ys, 0.0f), 127.0f);
    const float xc = fminf(fmaxf(xs, 0.0f), 127.0f);
    const int   y0 = (int)floorf(yc);
    const int   x0 = (int)floorf(xc);
    const float ly = yc - (float)y0;
    const float lx = xc - (float)x0;
    const int   y1i = min(y0 + 1, 127);
    const int   x0f = min(x0, 126);
    const int   yr  = rrow ? y1i : y0;
    const float wy  = rrow ? ly : (1.0f - ly);

    float wA, wB;
    if (x0 <= 126) { wA = 1.0f - lx; wB = lx; }
    else           { wA = 0.0f;      wB = 1.0f; }
    const float wyv = valid ? wy * (1.0f / 16.0f) : 0.0f;
    wA *= wyv;
    wB *= wyv;

    const int po = yr * 128 + x0f;
    const float* plane0 = x + ((size_t)(b * 256) << 14) + po;

    const int cbase = waveId * 64;
    float resv = 0.0f;
    #pragma unroll
    for (int i = 0; i < 32; ++i) {
        const int c = cbase + 2 * i + chHalf;
        const f2  v = *(const f2*)(plane0 + ((size_t)c << 14));
        float p = wA * v.x + wB * v.y;
        p += __shfl_xor(p, 1);
        p += __shfl_xor(p, 2);
        p += __shfl_xor(p, 4);
        p += __shfl_xor(p, 8);
        p += __shfl_xor(p, 16);
        const float q    = __shfl_xor(p, 32);
        const float mine = ((lane & 1) == chHalf) ? p : q;
        if ((lane >> 1) == i) resv = mine;
    }
    out[((size_t)(n * 256 + cbase + lane)) * 49 + pq] = resv;
}

extern "C" void kernel_launch(void* const* d_in, const int* in_sizes, int n_in,
                              void* d_out, int out_size, void* d_ws, size_t ws_size,
                              hipStream_t stream) {
    const float* x    = (const float*)d_in[0];
    const float* rois = (const float*)d_in[1];
    const float* offs = (const float*)d_in[2];
    float*       out  = (float*)d_out;

    if (ws_size >= XT_BYTES) {
        _Float16* xt = (_Float16*)d_ws;
        transpose_kernel<<<4096, 256, 0, stream>>>(x, xt);
        dcn_pool_roi_kernel<<<NROIS, 512, 0, stream>>>(xt, rois, offs, out);
    } else {
        dcn_pool_kernel<<<NROIS * 49, 256, 0, stream>>>(x, rois, offs, out);
    }
}

// Round 10
// 119.937 us; speedup vs baseline: 1.0383x; 1.0383x over previous
//
#include <hip/hip_runtime.h>

#define NROIS 512
#define CH    256
#define SCALE 0.0625f
#define GAMMA 0.1f

typedef _Float16 h4 __attribute__((ext_vector_type(4)));

// Transposed fp16 copy of x: (B,C,H,W) -> (B,H,W,C) halves. 32 MiB.
#define XT_BYTES ((size_t)4 * 128 * 128 * 256 * 2)

// ---------------------------------------------------------------------------
// Kernel 1: tiled transpose per batch: 256 (C) x 16384 (HW) -> 16384 x 256,
// converting fp32 -> fp16 at the write. 64 MiB read + 32 MiB write ~= HBM
// roofline (~16 us). [R8 post-mortem: non-temporal hints here REGRESSED
// (+4.5 us) -> plain loads/stores. R4-R9 post-mortem: fusing this with the
// pool via inter-block handoff kills containers -> two kernels, final.]
// ---------------------------------------------------------------------------
__global__ __launch_bounds__(256) void transpose_kernel(
    const float* __restrict__ x, _Float16* __restrict__ xt)
{
    __shared__ float tile[64][65];           // [c][p], +1 pad
    const int bid = blockIdx.x;              // 256 p-tiles * 4 c-tiles * 4 batches
    const int pt  = bid & 255;
    const int ct  = (bid >> 8) & 3;
    const int b   = bid >> 10;
    const int p0  = pt * 64, c0 = ct * 64;
    const size_t boff = (size_t)b * (256 * 16384);
    const int a = threadIdx.x & 15;          // float4 slot
    const int r = threadIdx.x >> 4;          // 0..15

    #pragma unroll
    for (int i = 0; i < 4; ++i) {            // coalesced float4 reads along HW
        const int cr = r + 16 * i;
        const float4 v = *(const float4*)(x + boff + (size_t)(c0 + cr) * 16384 + p0 + 4 * a);
        tile[cr][4 * a + 0] = v.x;
        tile[cr][4 * a + 1] = v.y;
        tile[cr][4 * a + 2] = v.z;
        tile[cr][4 * a + 3] = v.w;
    }
    __syncthreads();
    #pragma unroll
    for (int i = 0; i < 4; ++i) {            // coalesced half4 writes along C
        const int pr = r + 16 * i;
        h4 v;
        v.x = (_Float16)tile[4 * a + 0][pr];
        v.y = (_Float16)tile[4 * a + 1][pr];
        v.z = (_Float16)tile[4 * a + 2][pr];
        v.w = (_Float16)tile[4 * a + 3][pr];
        *(h4*)(xt + boff + (size_t)(p0 + pr) * 256 + c0 + 4 * a) = v;
    }
}

// ---------------------------------------------------------------------------
// Kernel 2: ONE BLOCK (512 thr, 8 waves) PER ROI on fp16 xt.
// Harness-verified round-3 kernel (119.96 us).
//  - PROLOGUE: threads 0..48 precompute per-bin records into LDS:
//    4 clamped row offsets, 4 clamped col offsets (duplicate-clamp: index
//    min(d, n-1); duplicated cells carry weight 0), and 16 premultiplied
//    wy*wx weights. Removes weight math from the serial loop.
//  - MAIN LOOP: branchless 16-load bins, 1-deep ping-pong pipeline:
//    issue bin i+1's loads, then FMA bin i under them (compiler counted
//    vmcnt keeps them in flight). All buffer indices compile-time.
//    fmaf(0, finite, acc) == acc, so dup cells are exact.
// ---------------------------------------------------------------------------
__global__ __launch_bounds__(512, 4) void dcn_pool_roi_kernel(
    const _Float16* __restrict__ xt, const float* __restrict__ rois,
    const float* __restrict__ offs, float* __restrict__ out)
{
    __shared__ __align__(16) float res[CH * 49];    // 50176 B
    __shared__ __align__(16) int   s_ro[49][4];     // row element offsets
    __shared__ __align__(16) int   s_xo[49][4];     // col element offsets
    __shared__ __align__(16) float s_w[49][16];     // premultiplied weights
    const int n = blockIdx.x;

    const float* r = rois + n * 5;
    const int   b  = (int)r[0];
    const float x1 = r[1] * SCALE - 0.5f;
    const float y1 = r[2] * SCALE - 0.5f;
    const float rw = fmaxf(r[3] * SCALE - 0.5f - x1, 1.0f);
    const float rh = fmaxf(r[4] * SCALE - 0.5f - y1, 1.0f);
    const float bw = rw * (1.0f / 7.0f);
    const float bh = rh * (1.0f / 7.0f);

    const int t = threadIdx.x;

    // ---- prologue: per-bin weight records (threads 0..48) ----
    if (t < 49) {
        const int ph = t / 7, pw = t - ph * 7;
        const float offx = GAMMA * rw * offs[n * 98 + t];
        const float offy = GAMMA * rh * offs[n * 98 + 49 + t];
        const float xb = x1 + pw * bw + offx;
        const float yb = y1 + ph * bh + offy;
        const float qy = 0.25f * bh, qx = 0.25f * bw;

        float wy0 = 0.f, wy1 = 0.f, wy2 = 0.f, wy3 = 0.f;
        const int ymin = (int)fminf(fmaxf(yb + 0.5f * qy, 0.0f), 127.0f);
        #pragma unroll
        for (int iy = 0; iy < 4; ++iy) {
            const float ys = yb + ((float)iy + 0.5f) * qy;
            const float vy = ((ys > -1.0f) && (ys < 128.0f)) ? 0.25f : 0.0f;
            const float yc = fminf(fmaxf(ys, 0.0f), 127.0f);
            const int   y0 = (int)yc;            // >= ymin, <= ymin+2
            const float ly = yc - (float)y0;
            const float hy = 1.0f - ly;
            const int   dy = y0 - ymin;
            const float ha = hy * vy, la = ly * vy;
            wy0 += (dy == 0) ? ha : 0.0f;
            wy1 += (dy == 0) ? la : ((dy == 1) ? ha : 0.0f);
            wy2 += (dy == 1) ? la : ((dy == 2) ? ha : 0.0f);
            wy3 += (dy == 2) ? la : 0.0f;
        }
        float wx0 = 0.f, wx1 = 0.f, wx2 = 0.f, wx3 = 0.f;
        const int xmin = (int)fminf(fmaxf(xb + 0.5f * qx, 0.0f), 127.0f);
        #pragma unroll
        for (int ix = 0; ix < 4; ++ix) {
            const float xs = xb + ((float)ix + 0.5f) * qx;
            const float vx = ((xs > -1.0f) && (xs < 128.0f)) ? 0.25f : 0.0f;
            const float xc = fminf(fmaxf(xs, 0.0f), 127.0f);
            const int   x0 = (int)xc;
            const float lx = xc - (float)x0;
            const float hx = 1.0f - lx;
            const int   dx = x0 - xmin;
            const float ha = hx * vx, la = lx * vx;
            wx0 += (dx == 0) ? ha : 0.0f;
            wx1 += (dx == 0) ? la : ((dx == 1) ? ha : 0.0f);
            wx2 += (dx == 1) ? la : ((dx == 2) ? ha : 0.0f);
            wx3 += (dx == 2) ? la : 0.0f;
        }
        const int y0max = (int)fminf(fmaxf(yb + 3.5f * qy, 0.0f), 127.0f);
        const int x0max = (int)fminf(fmaxf(xb + 3.5f * qx, 0.0f), 127.0f);
        const int ny = min(y0max - ymin + 2, 128 - ymin);   // 1..4
        const int nx = min(x0max - xmin + 2, 128 - xmin);   // 1..4

        const float wyv[4] = {wy0, wy1, wy2, wy3};
        const float wxv[4] = {wx0, wx1, wx2, wx3};
        #pragma unroll
        for (int dy = 0; dy < 4; ++dy)
            s_ro[t][dy] = (ymin + min(dy, ny - 1)) * (128 * 256);
        #pragma unroll
        for (int dx = 0; dx < 4; ++dx)
            s_xo[t][dx] = (xmin + min(dx, nx - 1)) * 256;
        #pragma unroll
        for (int dy = 0; dy < 4; ++dy)
            #pragma unroll
            for (int dx = 0; dx < 4; ++dx)
                s_w[t][dy * 4 + dx] = wyv[dy] * wxv[dx];
    }
    __syncthreads();

    const int lane = threadIdx.x & 63;
    const int wv   = __builtin_amdgcn_readfirstlane(threadIdx.x >> 6); // 0..7
    const _Float16* base = xt + ((size_t)b << 22) + 4 * lane;

    h4 v0[4][4], v1[4][4];

#define ISSUE(V, BIN) do {                                                  \
        const int4 ro = *(const int4*)s_ro[BIN];                            \
        const int4 xo = *(const int4*)s_xo[BIN];                            \
        V[0][0] = *(const h4*)(base + ro.x + xo.x);                         \
        V[0][1] = *(const h4*)(base + ro.x + xo.y);                         \
        V[0][2] = *(const h4*)(base + ro.x + xo.z);                         \
        V[0][3] = *(const h4*)(base + ro.x + xo.w);                         \
        V[1][0] = *(const h4*)(base + ro.y + xo.x);                         \
        V[1][1] = *(const h4*)(base + ro.y + xo.y);                         \
        V[1][2] = *(const h4*)(base + ro.y + xo.z);                         \
        V[1][3] = *(const h4*)(base + ro.y + xo.w);                         \
        V[2][0] = *(const h4*)(base + ro.z + xo.x);                         \
        V[2][1] = *(const h4*)(base + ro.z + xo.y);                         \
        V[2][2] = *(const h4*)(base + ro.z + xo.z);                         \
        V[2][3] = *(const h4*)(base + ro.z + xo.w);                         \
        V[3][0] = *(const h4*)(base + ro.w + xo.x);                         \
        V[3][1] = *(const h4*)(base + ro.w + xo.y);                         \
        V[3][2] = *(const h4*)(base + ro.w + xo.z);                         \
        V[3][3] = *(const h4*)(base + ro.w + xo.w);                         \
    } while (0)

#define FMA_STORE(V, BIN) do {                                              \
        const float4 w0 = *(const float4*)&s_w[BIN][0];                     \
        const float4 w1 = *(const float4*)&s_w[BIN][4];                     \
        const float4 w2 = *(const float4*)&s_w[BIN][8];                     \
        const float4 w3 = *(const float4*)&s_w[BIN][12];                    \
        float4 acc = make_float4(0.0f, 0.0f, 0.0f, 0.0f);                   \
        const float wgt[16] = {w0.x, w0.y, w0.z, w0.w,                      \
                               w1.x, w1.y, w1.z, w1.w,                      \
                               w2.x, w2.y, w2.z, w2.w,                      \
                               w3.x, w3.y, w3.z, w3.w};                     \
        _Pragma("unroll")                                                   \
        for (int dy = 0; dy < 4; ++dy) {                                    \
            _Pragma("unroll")                                               \
            for (int dx = 0; dx < 4; ++dx) {                                \
                const float w  = wgt[dy * 4 + dx];                          \
                const h4    hv = V[dy][dx];                                 \
                acc.x = fmaf(w, (float)hv.x, acc.x);                        \
                acc.y = fmaf(w, (float)hv.y, acc.y);                        \
                acc.z = fmaf(w, (float)hv.z, acc.z);                        \
                acc.w = fmaf(w, (float)hv.w, acc.w);                        \
            }                                                               \
        }                                                                   \
        float* rp = res + (4 * lane) * 49 + (BIN);                          \
        rp[0]   = acc.x;                                                    \
        rp[49]  = acc.y;                                                    \
        rp[98]  = acc.z;                                                    \
        rp[147] = acc.w;                                                    \
    } while (0)

    // 1-deep ping-pong pipeline over this wave's bins (wv, wv+8, ...).
    ISSUE(v0, wv);
    #pragma unroll
    for (int i = 0; i < 7; ++i) {
        const int bin  = wv + 8 * i;
        if (bin >= 49) break;                 // wave-uniform
        const int nbin = bin + 8;
        if (i & 1) {
            if (nbin < 49) ISSUE(v0, nbin);
            FMA_STORE(v1, bin);
        } else {
            if (nbin < 49) ISSUE(v1, nbin);
            FMA_STORE(v0, bin);
        }
    }
#undef ISSUE
#undef FMA_STORE

    __syncthreads();

    // Coalesced epilogue: 12544 floats = 3136 float4, contiguous full-line
    // span owned entirely by this block (no partial-line RMW).
    float*        ob = out + (size_t)n * (CH * 49);
    const float4* rs = (const float4*)res;
    float4*       od = (float4*)ob;
    for (int i = threadIdx.x; i < 3136; i += 512) od[i] = rs[i];
}

// ---------------------------------------------------------------------------
// Fallback (round-1 kernel) if d_ws is too small. Reads fp32 x directly.
// ---------------------------------------------------------------------------
struct __attribute__((packed, aligned(4))) f2 { float x, y; };

__global__ __launch_bounds__(256) void dcn_pool_kernel(
    const float* __restrict__ x, const float* __restrict__ rois,
    const float* __restrict__ offs, float* __restrict__ out)
{
    const int bin = blockIdx.x;
    const int n   = bin / 49;
    const int pq  = bin - n * 49;
    const int ph  = pq / 7;
    const int pw  = pq - ph * 7;

    const float* r = rois + n * 5;
    const int   b  = (int)r[0];
    const float x1 = r[1] * SCALE - 0.5f;
    const float y1 = r[2] * SCALE - 0.5f;
    const float x2 = r[3] * SCALE - 0.5f;
    const float y2 = r[4] * SCALE - 0.5f;
    const float rw = fmaxf(x2 - x1, 1.0f);
    const float rh = fmaxf(y2 - y1, 1.0f);
    const float bw = rw * (1.0f / 7.0f);
    const float bh = rh * (1.0f / 7.0f);
    const float offx = GAMMA * rw * offs[n * 98 + pq];
    const float offy = GAMMA * rh * offs[n * 98 + 49 + pq];
    const float xb = x1 + pw * bw + offx;
    const float yb = y1 + ph * bh + offy;

    const int tid    = threadIdx.x;
    const int lane   = tid & 63;
    const int waveId = tid >> 6;
    const int idx    = lane & 31;
    const int s      = idx >> 1;
    const int rrow   = idx & 1;
    const int chHalf = lane >> 5;

    const int   iy = s >> 2, ix = s & 3;
    const float ys = yb + ((float)iy + 0.5f) * 0.25f * bh;
    const float xs = xb + ((float)ix + 0.5f) * 0.25f * bw;
    const bool  valid = (ys > -1.0f) & (ys < 128.0f) & (xs > -1.0f) & (xs < 128.0f);
    const float yc = fminf(fmaxf(ys, 0.0f), 127.0f);
    const float xc = fminf(fmaxf(xs, 0.0f), 127.0f);
    const int   y0 = (int)floorf(yc);
    const int   x0 = (int)floorf(xc);
    const float ly = yc - (float)y0;
    const float lx = xc - (float)x0;
    const int   y1i = min(y0 + 1, 127);
    const int   x0f = min(x0, 126);
    const int   yr  = rrow ? y1i : y0;
    const float wy  = rrow ? ly : (1.0f - ly);

    float wA, wB;
    if (x0 <= 126) { wA = 1.0f - lx; wB = lx; }
    else           { wA = 0.0f;      wB = 1.0f; }
    const float wyv = valid ? wy * (1.0f / 16.0f) : 0.0f;
    wA *= wyv;
    wB *= wyv;

    const int po = yr * 128 + x0f;
    const float* plane0 = x + ((size_t)(b * 256) << 14) + po;

    const int cbase = waveId * 64;
    float resv = 0.0f;
    #pragma unroll
    for (int i = 0; i < 32; ++i) {
        const int c = cbase + 2 * i + chHalf;
        const f2  v = *(const f2*)(plane0 + ((size_t)c << 14));
        float p = wA * v.x + wB * v.y;
        p += __shfl_xor(p, 1);
        p += __shfl_xor(p, 2);
        p += __shfl_xor(p, 4);
        p += __shfl_xor(p, 8);
        p += __shfl_xor(p, 16);
        const float q    = __shfl_xor(p, 32);
        const float mine = ((lane & 1) == chHalf) ? p : q;
        if ((lane >> 1) == i) resv = mine;
    }
    out[((size_t)(n * 256 + cbase + lane)) * 49 + pq] = resv;
}

extern "C" void kernel_launch(void* const* d_in, const int* in_sizes, int n_in,
                              void* d_out, int out_size, void* d_ws, size_t ws_size,
                              hipStream_t stream) {
    const float* x    = (const float*)d_in[0];
    const float* rois = (const float*)d_in[1];
    const float* offs = (const float*)d_in[2];
    float*       out  = (float*)d_out;

    if (ws_size >= XT_BYTES) {
        _Float16* xt = (_Float16*)d_ws;
        transpose_kernel<<<4096, 256, 0, stream>>>(x, xt);
        dcn_pool_roi_kernel<<<NROIS, 512, 0, stream>>>(xt, rois, offs, out);
    } else {
        dcn_pool_kernel<<<NROIS * 49, 256, 0, stream>>>(x, rois, offs, out);
    }
}